// Round 2
// baseline (22940.895 us; speedup 1.0000x reference)
//
#include <hip/hip_runtime.h>

// Problem dims
constexpr int TSTEPS = 512;
constexpr int FDIM   = 128;
constexpr int HDIM   = 256;
constexpr int G4H    = 4 * HDIM;  // 1024
// Decomposition: 16 groups x 16 rows; 16 slices x 16 hidden units (x4 gates = 64 cols)
constexpr int NG  = 16;
constexpr int RG  = 16;
constexpr int NSL = 16;
constexpr int JJ  = 16;
constexpr int CB  = 64;
constexpr int PR  = 257;  // part[] row stride (padded: spreads banks in reduce reads)

// Workspace: flags[16*16] then h double-buffer [2][16 groups][256*16]
constexpr size_t FLAGS_BYTES = NG * NSL * sizeof(unsigned);         // 1 KB
constexpr size_t HBUF_OFF    = 1024;
constexpr size_t HBUF_FLOATS = 2ull * NG * HDIM * RG;               // 131072
constexpr size_t WS_NEED     = HBUF_OFF + HBUF_FLOATS * 4;

__device__ __forceinline__ float sigmf(float z) { return 1.f / (1.f + __expf(-z)); }
__device__ __forceinline__ float tanhf_fast(float z) {
    float a = fabsf(z);
    float e = __expf(-2.f * a);
    float r = (1.f - e) / (1.f + e);
    return z < 0.f ? -r : r;
}

// 256 blocks (1/CU) x 256 threads (4 waves). Block (g,s): rows [16g,16g+16),
// hidden units [16s,16s+16) x 4 gates. Weights resident in VGPRs (lane=col;
// wave owns h-rows [64w,64w+64) + f-rows [32w,32w+32)).
// Cross-block h exchange: RELAXED device-scope (sc0sc1/MALL) ops ONLY — no
// acquire/release (those emit per-step L2 wbinv = round-1's 30us/step stall).
extern "C" __global__ void __launch_bounds__(256, 1)
lstm_persist(const float* __restrict__ x, const float* __restrict__ kern,
             const float* __restrict__ rker, float* __restrict__ hbuf,
             unsigned* __restrict__ flags)
{
    const int g    = blockIdx.x & 15;
    const int s    = blockIdx.x >> 4;
    const int tid  = threadIdx.x;
    const int wave = tid >> 6;
    const int lane = tid & 63;

    __shared__ __align__(16) float hs[(HDIM + FDIM) * RG];  // [k'][r]: h rows 0..255, x rows 256..383
    __shared__ __align__(16) float part[RG * PR];           // [r][wave*64+c], stride 257

    float* hb0 = hbuf + (size_t)g * (HDIM * RG);
    float* hb1 = hbuf + (size_t)(NG * HDIM * RG) + (size_t)g * (HDIM * RG);
    unsigned* fl = flags + g * NSL;

    // ---- Resident weights (one-time, plain cached loads)
    const int c    = lane;
    const int gate = c >> 4;
    const int jjc  = c & 15;
    const int colg = gate * HDIM + s * JJ + jjc;
    float wreg[96];
#pragma unroll
    for (int i = 0; i < 64; ++i)
        wreg[i] = rker[(size_t)(wave * 64 + i) * G4H + colg];
#pragma unroll
    for (int i = 0; i < 32; ++i)
        wreg[64 + i] = kern[(size_t)(wave * 32 + i) * G4H + colg];

    // ---- Nonlinearity mapping: thread <-> (row rr, unit jr)
    const int rr = tid & 15;
    const int jr = tid >> 4;
    float cstate = 0.f;
    const int hw_off = (s * JJ + jr) * RG + rr;

    const float* xg = x + (size_t)(g * RG) * TSTEPS * FDIM;

#pragma unroll 1
    for (int t = 0; t < TSTEPS; ++t) {
        const float* hb_cur = (t & 1) ? hb1 : hb0;  // holds h(t)
        float*       hb_nxt = (t & 1) ? hb0 : hb1;  // receives h(t+1)

        // ---- Stage x(t) -> hs x-region (pre-barrier; conflicts overlap the wait)
#pragma unroll
        for (int half = 0; half < 2; ++half) {
            const int ci = tid + half * 256;
            const int r0 = ci >> 5, fc = ci & 31;
            const float4 xv = *reinterpret_cast<const float4*>(
                xg + ((size_t)r0 * TSTEPS + t) * FDIM + fc * 4);
            const int kb = (HDIM + fc * 4) * RG + r0;
            hs[kb] = xv.x; hs[kb + RG] = xv.y; hs[kb + 2 * RG] = xv.z; hs[kb + 3 * RG] = xv.w;
        }
        __syncthreads();  // S_a: x staged; also orders part reduce(t-1) before part writes(t)

        float acc[16];
#pragma unroll
        for (int i = 0; i < 16; ++i) acc[i] = 0.f;

        // ---- x-part GEMM (h-independent): overlaps producer lag
#pragma unroll
        for (int i = 0; i < 32; ++i) {
            const float w = wreg[64 + i];
            const float* hrow = &hs[(HDIM + wave * 32 + i) * RG];
#pragma unroll
            for (int rq = 0; rq < 4; ++rq) {  // uniform-address ds_read_b128 = broadcast
                const float4 hv = *reinterpret_cast<const float4*>(hrow + rq * 4);
                acc[rq * 4 + 0] += w * hv.x;
                acc[rq * 4 + 1] += w * hv.y;
                acc[rq * 4 + 2] += w * hv.z;
                acc[rq * 4 + 3] += w * hv.w;
            }
        }

        // ---- Group barrier: all 16 slices of group g at step >= t (16 parallel flag polls)
        if (wave == 0) {
            const unsigned tgt = (unsigned)t;
            while (true) {
                unsigned f = 0xFFFFFFFFu;
                if (lane < NSL)
                    f = __hip_atomic_load(&fl[lane], __ATOMIC_RELAXED, __HIP_MEMORY_SCOPE_AGENT);
                if (__all((int)(f >= tgt))) break;
            }
        }
        asm volatile("" ::: "memory");
        __syncthreads();  // S_c

        // ---- Stage h(t): device-scope (MALL) loads, contiguous per wave-instr,
        //      conflict-free LDS stores (addr = q*256+tid)
#pragma unroll
        for (int q = 0; q < 16; ++q) {
            const int idx = q * 256 + tid;
            hs[idx] = __hip_atomic_load(&hb_cur[idx], __ATOMIC_RELAXED, __HIP_MEMORY_SCOPE_AGENT);
        }
        __syncthreads();  // S_d

        // ---- h-part GEMM
#pragma unroll
        for (int i = 0; i < 64; ++i) {
            const float w = wreg[i];
            const float* hrow = &hs[(wave * 64 + i) * RG];
#pragma unroll
            for (int rq = 0; rq < 4; ++rq) {
                const float4 hv = *reinterpret_cast<const float4*>(hrow + rq * 4);
                acc[rq * 4 + 0] += w * hv.x;
                acc[rq * 4 + 1] += w * hv.y;
                acc[rq * 4 + 2] += w * hv.z;
                acc[rq * 4 + 3] += w * hv.w;
            }
        }

        // ---- Partials: part[r][wave*64+lane] — lane-contiguous scalar stores, conflict-free
#pragma unroll
        for (int r = 0; r < 16; ++r)
            part[r * PR + wave * CB + lane] = acc[r];
        __syncthreads();  // S_b

        // ---- Reduce 4 wave-partials + gates + cell update
        float z0 = 0.f, z1 = 0.f, z2 = 0.f, z3 = 0.f;
#pragma unroll
        for (int w4 = 0; w4 < 4; ++w4) {
            const float* pw = &part[rr * PR + w4 * CB];
            z0 += pw[0 * JJ + jr];
            z1 += pw[1 * JJ + jr];
            z2 += pw[2 * JJ + jr];
            z3 += pw[3 * JJ + jr];
        }
        const float ai = sigmf(z0);
        const float af = sigmf(z1);
        const float ag = tanhf_fast(z2);
        const float ao = sigmf(z3);
        cstate = af * cstate + ai * ag;
        const float hnew = ao * tanhf_fast(cstate);

        // Device-scope relaxed store -> MALL (coherent cross-XCD), lane-contiguous
        __hip_atomic_store(&hb_nxt[hw_off], hnew, __ATOMIC_RELAXED, __HIP_MEMORY_SCOPE_AGENT);

        __syncthreads();  // S_e: drains vmcnt(0) -> h stores MALL-visible block-wide
        if (tid == 0) {
            asm volatile("" ::: "memory");
            __hip_atomic_store(&fl[s], (unsigned)(t + 1), __ATOMIC_RELAXED, __HIP_MEMORY_SCOPE_AGENT);
        }
    }
    // h(512) lives in hb[512&1] = buffer 0.
}

// Head: out[b] = relu(h[b]@w1 + b1) @ w2 + b2. One block per batch row.
extern "C" __global__ void __launch_bounds__(128, 1)
head_kernel(const float* __restrict__ hbuf0, const float* __restrict__ w1,
            const float* __restrict__ b1, const float* __restrict__ w2,
            const float* __restrict__ b2, float* __restrict__ out)
{
    const int b = blockIdx.x;
    const int g = b >> 4, r = b & 15;
    const int tid = threadIdx.x;
    __shared__ float lh[HDIM];
    __shared__ float hid[128];
    const float* hbg = hbuf0 + (size_t)g * (HDIM * RG);
    lh[tid]       = hbg[(size_t)tid * RG + r];
    lh[tid + 128] = hbg[(size_t)(tid + 128) * RG + r];
    hid[tid] = 0.f;
    __syncthreads();
    if (tid < 100) {
        float acc = b1[tid];
#pragma unroll 8
        for (int k = 0; k < HDIM; ++k) acc += lh[k] * w1[k * 100 + tid];
        hid[tid] = fmaxf(acc, 0.f);
    }
    __syncthreads();
    if (tid < 64) {
        float v = hid[tid] * w2[tid];
        const int j2 = tid + 64;
        v += (j2 < 100) ? hid[j2] * w2[j2] : 0.f;
        for (int off = 32; off; off >>= 1) v += __shfl_down(v, off, 64);
        if (tid == 0) out[b] = v + b2[0];
    }
}

extern "C" void kernel_launch(void* const* d_in, const int* in_sizes, int n_in,
                              void* d_out, int out_size, void* d_ws, size_t ws_size,
                              hipStream_t stream)
{
    const float* x    = (const float*)d_in[0];
    const float* kern = (const float*)d_in[1];
    const float* rker = (const float*)d_in[2];
    const float* w1   = (const float*)d_in[3];
    const float* b1   = (const float*)d_in[4];
    const float* w2   = (const float*)d_in[5];
    const float* b2   = (const float*)d_in[6];
    float* out = (float*)d_out;

    unsigned* flags = (unsigned*)d_ws;
    float* hbuf     = (float*)((char*)d_ws + HBUF_OFF);

    // Zero flags + h double-buffer (h(0)=0). Stream-ordered, capture-safe.
    hipMemsetAsync(d_ws, 0, WS_NEED, stream);

    lstm_persist<<<dim3(256), dim3(256), 0, stream>>>(x, kern, rker, hbuf, flags);
    head_kernel<<<dim3(256), dim3(128), 0, stream>>>(hbuf /*buffer 0*/, w1, b1, w2, b2, out);
}

// Round 3
// 22335.043 us; speedup vs baseline: 1.0271x; 1.0271x over previous
//
#include <hip/hip_runtime.h>

// Problem dims
constexpr int TSTEPS = 512;
constexpr int FDIM   = 128;
constexpr int HDIM   = 256;
constexpr int G4H    = 4 * HDIM;  // 1024
// Decomposition: 16 groups x 16 rows; 16 slices x 16 hidden units (x4 gates = 64 cols)
constexpr int NG  = 16;
constexpr int RG  = 16;
constexpr int NSL = 16;
constexpr int JJ  = 16;
constexpr int CB  = 64;
constexpr int PR  = 257;  // part[] row stride

// Workspace: flags[16*16] then h double-buffer [2][16 groups][256*16]
constexpr size_t HBUF_OFF    = 1024;
constexpr size_t HBUF_FLOATS = 2ull * NG * HDIM * RG;  // 131072
constexpr size_t WS_NEED     = HBUF_OFF + HBUF_FLOATS * 4;

typedef float f32x4 __attribute__((ext_vector_type(4)));

__device__ __forceinline__ float sigmf(float z) { return 1.f / (1.f + __expf(-z)); }
__device__ __forceinline__ float tanhf_fast(float z) {
    float a = fabsf(z);
    float e = __expf(-2.f * a);
    float r = (1.f - e) / (1.f + e);
    return z < 0.f ? -r : r;
}

// Device-scope (MALL-coherent, L1/L2-bypass) 16B load/store via sc0 sc1.
// NOTE: compiler does NOT track inline-asm vmem — wait_vm0() ("memory" clobber)
// must precede any memory op consuming the result.
__device__ __forceinline__ f32x4 load_x4_dev(const float* base, int byte_off) {
    f32x4 v;
    asm volatile("global_load_dwordx4 %0, %1, %2 sc0 sc1"
                 : "=v"(v) : "v"(byte_off), "s"(base) : "memory");
    return v;
}
__device__ __forceinline__ void store_x4_dev(float* base, int byte_off, f32x4 v) {
    asm volatile("global_store_dwordx4 %0, %1, %2 sc0 sc1"
                 :: "v"(byte_off), "v"(v), "s"(base) : "memory");
}
__device__ __forceinline__ void wait_vm0() {
    asm volatile("s_waitcnt vmcnt(0)" ::: "memory");
}

// 256 blocks (1/CU) x 256 threads (4 waves). Block (g,s): rows [16g,16g+16),
// hidden units [16s,16s+16) x 4 gates. Weights VGPR-resident (lane=col; wave
// owns h-rows [64w,64w+64) + x-rows [32w,32w+32)). All cross-block traffic:
// coalesced dwordx4 sc0sc1 + throttled flag polls. No acquire/release (L2 wbinv).
extern "C" __global__ void __launch_bounds__(256, 1)
lstm_persist(const float* __restrict__ x, const float* __restrict__ kern,
             const float* __restrict__ rker, float* __restrict__ hbuf,
             unsigned* __restrict__ flags)
{
    const int g    = blockIdx.x & 15;   // all 16 blocks of a group: same blockIdx%8 -> same XCD (x reuse)
    const int s    = blockIdx.x >> 4;
    const int tid  = threadIdx.x;
    const int wave = tid >> 6;
    const int lane = tid & 63;

    __shared__ __align__(16) float hs[(HDIM + FDIM) * RG];  // [k'][r]: k'=0..255 h, 256..383 x
    __shared__ __align__(16) float part[RG * PR];
    __shared__ __align__(16) float hstage[HDIM];            // 256: block's h chunk, store restage

    float* hb0 = hbuf + (size_t)g * (HDIM * RG);
    float* hb1 = hbuf + (size_t)(NG * HDIM * RG) + (size_t)g * (HDIM * RG);
    unsigned* fl = flags + g * NSL;

    // ---- Resident weights (one-time plain cached loads)
    const int c    = lane;
    const int gate = c >> 4;
    const int jjc  = c & 15;
    const int colg = gate * HDIM + s * JJ + jjc;
    float wreg[96];
#pragma unroll
    for (int i = 0; i < 64; ++i)
        wreg[i] = rker[(size_t)(wave * 64 + i) * G4H + colg];
#pragma unroll
    for (int i = 0; i < 32; ++i)
        wreg[64 + i] = kern[(size_t)(wave * 32 + i) * G4H + colg];

    const int rr = tid & 15;   // row for nonlinearity
    const int jr = tid >> 4;   // unit for nonlinearity
    float cstate = 0.f;

    const float* xg = x + (size_t)(g * RG) * TSTEPS * FDIM;

#pragma unroll 1
    for (int t = 0; t < TSTEPS; ++t) {
        const float* hb_cur = (t & 1) ? hb1 : hb0;  // holds h(t)
        float*       hb_nxt = (t & 1) ? hb0 : hb1;  // receives h(t+1)

        // ---- Stage x(t): lane=row mapping -> 4-way LDS conflicts max (was 32-way)
        {
            const int xr = tid & 15;
#pragma unroll
            for (int half = 0; half < 2; ++half) {
                const int fc = (tid >> 4) + half * 16;  // 0..31
                const f32x4 xv = *reinterpret_cast<const f32x4*>(
                    xg + ((size_t)xr * TSTEPS + t) * FDIM + fc * 4);
                const int kb = (HDIM + fc * 4) * RG + xr;
                hs[kb] = xv[0]; hs[kb + RG] = xv[1]; hs[kb + 2 * RG] = xv[2]; hs[kb + 3 * RG] = xv[3];
            }
        }
        __syncthreads();  // S_a

        float acc[16];
#pragma unroll
        for (int i = 0; i < 16; ++i) acc[i] = 0.f;

        // ---- x-part GEMM (h-independent; overlaps producer lag)
#pragma unroll
        for (int i = 0; i < 32; ++i) {
            const float w = wreg[64 + i];
            const float* hrow = &hs[(HDIM + wave * 32 + i) * RG];
#pragma unroll
            for (int rq = 0; rq < 4; ++rq) {  // uniform-addr ds_read_b128 = broadcast, conflict-free
                const f32x4 hv = *reinterpret_cast<const f32x4*>(hrow + rq * 4);
                acc[rq * 4 + 0] += w * hv[0];
                acc[rq * 4 + 1] += w * hv[1];
                acc[rq * 4 + 2] += w * hv[2];
                acc[rq * 4 + 3] += w * hv[3];
            }
        }

        // ---- Group barrier: throttled poll (s_sleep backoff kills MALL congestion)
        if (wave == 0) {
            const unsigned tgt = (unsigned)t;
            while (true) {
                unsigned f = 0xFFFFFFFFu;
                if (lane < NSL)
                    f = __hip_atomic_load(&fl[lane], __ATOMIC_RELAXED, __HIP_MEMORY_SCOPE_AGENT);
                if (__all((int)(f >= tgt))) break;
                __builtin_amdgcn_s_sleep(2);
            }
        }
        asm volatile("" ::: "memory");
        __syncthreads();  // S_c

        // ---- Stage h(t): 4 coalesced dwordx4 sc0sc1 loads/thread, one waitcnt, b128 LDS stores
        {
            f32x4 hv[4];
#pragma unroll
            for (int q = 0; q < 4; ++q)
                hv[q] = load_x4_dev(hb_cur, (q * 256 + tid) * 16);
            wait_vm0();
#pragma unroll
            for (int q = 0; q < 4; ++q)
                *reinterpret_cast<f32x4*>(&hs[(q * 256 + tid) * 4]) = hv[q];
        }
        __syncthreads();  // S_d

        // ---- h-part GEMM
#pragma unroll
        for (int i = 0; i < 64; ++i) {
            const float w = wreg[i];
            const float* hrow = &hs[(wave * 64 + i) * RG];
#pragma unroll
            for (int rq = 0; rq < 4; ++rq) {
                const f32x4 hv = *reinterpret_cast<const f32x4*>(hrow + rq * 4);
                acc[rq * 4 + 0] += w * hv[0];
                acc[rq * 4 + 1] += w * hv[1];
                acc[rq * 4 + 2] += w * hv[2];
                acc[rq * 4 + 3] += w * hv[3];
            }
        }

        // ---- Partials: part[r][wave*64+lane] — 2-way max (free)
#pragma unroll
        for (int r = 0; r < 16; ++r)
            part[r * PR + wave * CB + lane] = acc[r];
        __syncthreads();  // S_b

        // ---- Reduce + gates + cell update
        float z0 = 0.f, z1 = 0.f, z2 = 0.f, z3 = 0.f;
#pragma unroll
        for (int w4 = 0; w4 < 4; ++w4) {
            const float* pw = &part[rr * PR + w4 * CB];
            z0 += pw[0 * JJ + jr];
            z1 += pw[1 * JJ + jr];
            z2 += pw[2 * JJ + jr];
            z3 += pw[3 * JJ + jr];
        }
        const float ai = sigmf(z0);
        const float af = sigmf(z1);
        const float ag = tanhf_fast(z2);
        const float ao = sigmf(z3);
        cstate = af * cstate + ai * ag;
        const float hnew = ao * tanhf_fast(cstate);

        // ---- Restage h chunk (local offset jr*16+rr == tid), then ONE coalesced
        //      wave0 dwordx4 sc0sc1 store (1 KB), waitcnt, flag store.
        hstage[tid] = hnew;
        __syncthreads();  // S_f
        if (wave == 0) {
            const f32x4 hv4 = *reinterpret_cast<const f32x4*>(&hstage[lane * 4]);
            store_x4_dev(hb_nxt + s * HDIM, lane * 16, hv4);
            wait_vm0();
            if (lane == 0)
                __hip_atomic_store(&fl[s], (unsigned)(t + 1), __ATOMIC_RELAXED, __HIP_MEMORY_SCOPE_AGENT);
        }
        // hstage reuse next step guarded by S_f(next); hs/part reuse guarded by S_a/S_d.
    }
    // h(512) lives in buffer 0.
}

// Head: out[b] = relu(h[b]@w1 + b1) @ w2 + b2. One block per batch row.
extern "C" __global__ void __launch_bounds__(128, 1)
head_kernel(const float* __restrict__ hbuf0, const float* __restrict__ w1,
            const float* __restrict__ b1, const float* __restrict__ w2,
            const float* __restrict__ b2, float* __restrict__ out)
{
    const int b = blockIdx.x;
    const int g = b >> 4, r = b & 15;
    const int tid = threadIdx.x;
    __shared__ float lh[HDIM];
    __shared__ float hid[128];
    const float* hbg = hbuf0 + (size_t)g * (HDIM * RG);
    lh[tid]       = hbg[(size_t)tid * RG + r];
    lh[tid + 128] = hbg[(size_t)(tid + 128) * RG + r];
    hid[tid] = 0.f;
    __syncthreads();
    if (tid < 100) {
        float acc = b1[tid];
#pragma unroll 8
        for (int k = 0; k < HDIM; ++k) acc += lh[k] * w1[k * 100 + tid];
        hid[tid] = fmaxf(acc, 0.f);
    }
    __syncthreads();
    if (tid < 64) {
        float v = hid[tid] * w2[tid];
        const int j2 = tid + 64;
        v += (j2 < 100) ? hid[j2] * w2[j2] : 0.f;
        for (int off = 32; off; off >>= 1) v += __shfl_down(v, off, 64);
        if (tid == 0) out[b] = v + b2[0];
    }
}

extern "C" void kernel_launch(void* const* d_in, const int* in_sizes, int n_in,
                              void* d_out, int out_size, void* d_ws, size_t ws_size,
                              hipStream_t stream)
{
    const float* x    = (const float*)d_in[0];
    const float* kern = (const float*)d_in[1];
    const float* rker = (const float*)d_in[2];
    const float* w1   = (const float*)d_in[3];
    const float* b1   = (const float*)d_in[4];
    const float* w2   = (const float*)d_in[5];
    const float* b2   = (const float*)d_in[6];
    float* out = (float*)d_out;

    unsigned* flags = (unsigned*)d_ws;
    float* hbuf     = (float*)((char*)d_ws + HBUF_OFF);

    // Zero flags + h double-buffer (h(0)=0). Stream-ordered, capture-safe.
    hipMemsetAsync(d_ws, 0, WS_NEED, stream);

    lstm_persist<<<dim3(256), dim3(256), 0, stream>>>(x, kern, rker, hbuf, flags);
    head_kernel<<<dim3(256), dim3(128), 0, stream>>>(hbuf /*buffer 0*/, w1, b1, w2, b2, out);
}

// Round 4
// 6061.602 us; speedup vs baseline: 3.7846x; 3.6847x over previous
//
#include <hip/hip_runtime.h>

// Dims
constexpr int TSTEPS = 512;
constexpr int FDIM   = 128;
constexpr int HDIM   = 256;
constexpr int G4H    = 1024;   // 4*H
constexpr int BATCH  = 256;
constexpr int NB     = 86;     // 84 blocks x 3 rows + 2 blocks x 2 rows = 256

typedef float f32x4 __attribute__((ext_vector_type(4)));

__device__ __forceinline__ float sigmf(float z) { return 1.f / (1.f + __expf(-z)); }
__device__ __forceinline__ float tanhf_fast(float z) {
    float a = fabsf(z);
    float e = __expf(-2.f * a);
    float r = (1.f - e) / (1.f + e);
    return z < 0.f ? -r : r;
}

// Zero-sync LSTM: each block owns up to 3 batch rows end-to-end; weights are
// streamed from L2 each step (1.5 MB, shared by ~11 blocks/XCD, L2-resident).
// No inter-block communication of any kind (rounds 1-3 showed per-step
// device-scope exchange costs ~40us/step regardless of mechanism).
// 512 threads: wave in [0,8): half=wave>>2 (K-split), gate=wave&3.
// Thread owns 4 consecutive columns of its gate -> dwordx4 weight loads.
// h(t) and x(t) packed in LDS as hx[k][4] (rows x4) -> 1 broadcast ds_read_b128/k.
extern "C" __global__ void __launch_bounds__(512, 1)
lstm_nosync(const float* __restrict__ x, const float* __restrict__ kern,
            const float* __restrict__ rker, float* __restrict__ hfinal)
{
    const int b    = blockIdx.x;
    const int base = (b < 84) ? 3 * b : 252 + 2 * (b - 84);
    const int nval = (b < 84) ? 3 : 2;            // valid rows (row 2 dead on last 2 blocks)
    const int tid  = threadIdx.x;
    const int wave = tid >> 6;
    const int lane = tid & 63;
    const int half = wave >> 2;                   // 0: k in [0,192), 1: k in [192,384)
    const int gate = wave & 3;                    // i,f,g,o
    const int coff = gate * 256 + lane * 4;       // 4 consecutive columns

    __shared__ __align__(16) float hx[384 * 4];   // [k][row]: k<256 = h, k>=256 = x(t)
    __shared__ __align__(16) float zp[2][3][G4H]; // K-half partials, 24 KB

    // h(0) = 0 (also zeroes the row-3 pad; pad never enters the FMAs)
    for (int i = tid; i < 384 * 4; i += 512) hx[i] = 0.f;

    // Nonlinearity mapping: item A = (rA = tid>>8, uA = tid&255); item B (tid<256) = (2, tid)
    const int rA = tid >> 8, uA = tid & 255;
    float cA = 0.f, cB = 0.f;

    // x staging mapping (threads 0..383): row = tid>>7, f = tid&127; clamp OOB dead row
    const int xr = tid >> 7;
    const int xf = tid & 127;
    const int xrow = min(base + xr, BATCH - 1);
    const float* xptr = x + ((size_t)xrow * TSTEPS) * FDIM + xf;

    const float* wr = rker + coff;   // rker[k][coff..coff+3] at wr + k*1024
    const float* wk = kern + coff;

#pragma unroll 1
    for (int t = 0; t < TSTEPS; ++t) {
        // ---- P0: stage x(t) (waves 0..5; disjoint from P2's h-region writes)
        if (tid < 384)
            hx[(256 + xf) * 4 + xr] = xptr[(size_t)t * FDIM];
        __syncthreads();  // B1: x(t) + h(t) staged; zp(t-1) fully consumed

        // ---- P1: K-half GEMM. Per k: 1 global dwordx4 (L2-hit) + 1 broadcast
        //      ds_read_b128 + 12 FMAs.
        f32x4 acc0 = {0.f, 0.f, 0.f, 0.f}, acc1 = acc0, acc2 = acc0;
        if (half == 0) {
#pragma unroll 4
            for (int k = 0; k < 192; ++k) {
                const f32x4 w  = *reinterpret_cast<const f32x4*>(wr + (size_t)k * G4H);
                const f32x4 hr = *reinterpret_cast<const f32x4*>(&hx[k * 4]);
#pragma unroll
                for (int j = 0; j < 4; ++j) {
                    acc0[j] += hr[0] * w[j];
                    acc1[j] += hr[1] * w[j];
                    acc2[j] += hr[2] * w[j];
                }
            }
        } else {
#pragma unroll 4
            for (int k = 192; k < 256; ++k) {
                const f32x4 w  = *reinterpret_cast<const f32x4*>(wr + (size_t)k * G4H);
                const f32x4 hr = *reinterpret_cast<const f32x4*>(&hx[k * 4]);
#pragma unroll
                for (int j = 0; j < 4; ++j) {
                    acc0[j] += hr[0] * w[j];
                    acc1[j] += hr[1] * w[j];
                    acc2[j] += hr[2] * w[j];
                }
            }
#pragma unroll 4
            for (int k = 256; k < 384; ++k) {
                const f32x4 w  = *reinterpret_cast<const f32x4*>(wk + (size_t)(k - 256) * G4H);
                const f32x4 hr = *reinterpret_cast<const f32x4*>(&hx[k * 4]);
#pragma unroll
                for (int j = 0; j < 4; ++j) {
                    acc0[j] += hr[0] * w[j];
                    acc1[j] += hr[1] * w[j];
                    acc2[j] += hr[2] * w[j];
                }
            }
        }
        // Partials: lane-consecutive b128 stores, conflict-free
        *reinterpret_cast<f32x4*>(&zp[half][0][coff]) = acc0;
        *reinterpret_cast<f32x4*>(&zp[half][1][coff]) = acc1;
        *reinterpret_cast<f32x4*>(&zp[half][2][coff]) = acc2;
        __syncthreads();  // B2

        // ---- P2: combine halves, gates, cell update; write h(t+1) into hx h-region
        {
            float z0 = zp[0][rA][0 * 256 + uA] + zp[1][rA][0 * 256 + uA];
            float z1 = zp[0][rA][1 * 256 + uA] + zp[1][rA][1 * 256 + uA];
            float z2 = zp[0][rA][2 * 256 + uA] + zp[1][rA][2 * 256 + uA];
            float z3 = zp[0][rA][3 * 256 + uA] + zp[1][rA][3 * 256 + uA];
            cA = sigmf(z1) * cA + sigmf(z0) * tanhf_fast(z2);
            hx[uA * 4 + rA] = sigmf(z3) * tanhf_fast(cA);
        }
        if (tid < 256) {
            float z0 = zp[0][2][0 * 256 + tid] + zp[1][2][0 * 256 + tid];
            float z1 = zp[0][2][1 * 256 + tid] + zp[1][2][1 * 256 + tid];
            float z2 = zp[0][2][2 * 256 + tid] + zp[1][2][2 * 256 + tid];
            float z3 = zp[0][2][3 * 256 + tid] + zp[1][2][3 * 256 + tid];
            cB = sigmf(z1) * cB + sigmf(z0) * tanhf_fast(z2);
            hx[tid * 4 + 2] = sigmf(z3) * tanhf_fast(cB);
        }
        // No barrier here: B1(next) separates P2 writes from next P1 reads;
        // P0(next) touches only the disjoint x-region.
    }
    __syncthreads();

    // ---- Final h store (row-major [b][u], coalesced); dead rows skipped
    hfinal[(size_t)(base + rA) * HDIM + uA] = hx[uA * 4 + rA];  // rA<2 <= nval always
    if (tid < 256 && nval == 3)
        hfinal[(size_t)(base + 2) * HDIM + tid] = hx[tid * 4 + 2];
}

// Head: out[b] = relu(h[b]@w1 + b1) @ w2 + b2. h is row-major [256][256].
extern "C" __global__ void __launch_bounds__(128, 1)
head_kernel(const float* __restrict__ h, const float* __restrict__ w1,
            const float* __restrict__ b1, const float* __restrict__ w2,
            const float* __restrict__ b2, float* __restrict__ out)
{
    const int b = blockIdx.x;
    const int tid = threadIdx.x;
    __shared__ float lh[HDIM];
    __shared__ float hid[128];
    lh[tid]       = h[(size_t)b * HDIM + tid];
    lh[tid + 128] = h[(size_t)b * HDIM + tid + 128];
    hid[tid] = 0.f;
    __syncthreads();
    if (tid < 100) {
        float acc = b1[tid];
#pragma unroll 8
        for (int k = 0; k < HDIM; ++k) acc += lh[k] * w1[k * 100 + tid];
        hid[tid] = fmaxf(acc, 0.f);
    }
    __syncthreads();
    if (tid < 64) {
        float v = hid[tid] * w2[tid];
        const int j2 = tid + 64;
        v += (j2 < 100) ? hid[j2] * w2[j2] : 0.f;
        for (int off = 32; off; off >>= 1) v += __shfl_down(v, off, 64);
        if (tid == 0) out[b] = v + b2[0];
    }
}

extern "C" void kernel_launch(void* const* d_in, const int* in_sizes, int n_in,
                              void* d_out, int out_size, void* d_ws, size_t ws_size,
                              hipStream_t stream)
{
    const float* x    = (const float*)d_in[0];
    const float* kern = (const float*)d_in[1];
    const float* rker = (const float*)d_in[2];
    const float* w1   = (const float*)d_in[3];
    const float* b1   = (const float*)d_in[4];
    const float* w2   = (const float*)d_in[5];
    const float* b2   = (const float*)d_in[6];
    float* out = (float*)d_out;

    float* hfinal = (float*)d_ws;  // 256 KB, fully overwritten each call

    lstm_nosync<<<dim3(NB), dim3(512), 0, stream>>>(x, kern, rker, hfinal);
    head_kernel<<<dim3(BATCH), dim3(128), 0, stream>>>(hfinal, w1, b1, w2, b2, out);
}